// Round 8
// baseline (25.753 us; speedup 1.0000x reference)
//
#include <hip/hip_runtime.h>

#define HALF 16
#define IMW  512
#define IMH  512
#define TSZ  32                // tile size (32x32, best measured geometry)
#define NT   16                // tiles per axis
#define TPI  256               // tiles per image
#define CAP  48                // per-tile list capacity (avg ~1.7, Poisson-safe)

typedef float f32x4 __attribute__((ext_vector_type(4)));

// Kernel A: bin landmarks into per-tile lists in d_ws.
// A 33-px patch span covers EXACTLY 2 tiles of 32 per axis (span 33 > 32),
// and clipping guarantees tx0,ty0 in [0,14] -> tiles {t0,t0+1} in range.
// ws layout: [cnt: B*TPI int32][lists: B*TPI*CAP float2]
__global__ __launch_bounds__(256)
void lm_bin_kernel(const float* __restrict__ landmarks, int L,
                   int* __restrict__ cnt, float2* __restrict__ lists)
{
    const int b = blockIdx.x;
    const int t = threadIdx.x;
    int* c = cnt + b * TPI;
    if (t < TPI) c[t] = 0;                 // zero this image's counters
    __syncthreads();
    if (t < L) {
        float2 lm = reinterpret_cast<const float2*>(landmarks)[(size_t)b * L + t];
        float x0 = fminf(fmaxf(lm.x, (float)HALF), (float)(IMW - 1 - HALF));
        float x1 = fminf(fmaxf(lm.y, (float)HALF), (float)(IMH - 1 - HALF));
        int i0 = (int)x0;                  // coords >= 16, trunc == floor
        int i1 = (int)x1;
        int tx0 = (i0 - HALF) >> 5;        // <= 14 (i0 <= 495)
        int ty0 = (i1 - HALF) >> 5;
        #pragma unroll
        for (int dy = 0; dy < 2; ++dy)
            #pragma unroll
            for (int dx = 0; dx < 2; ++dx) {
                int tile = (ty0 + dy) * NT + (tx0 + dx);
                int pos = atomicAdd(&c[tile], 1);
                if (pos < CAP)
                    lists[((size_t)b * TPI + tile) * CAP + pos] = make_float2(x0, x1);
            }
    }
}

// Kernel B: one block per 32x32 tile, 4 contiguous px/thread. No LDS, no
// barrier, no scan: count + list come from kernel A via L2-broadcast loads.
__global__ __launch_bounds__(256)
void lm_gather_kernel(const int* __restrict__ cnt,
                      const float2* __restrict__ lists,
                      float* __restrict__ out)
{
    const int bx   = blockIdx.x;
    const int b    = bx >> 8;              // TPI == 256
    const int tile = bx & (TPI - 1);
    const int tx   = tile & (NT - 1);
    const int ty   = tile >> 4;

    const int     n   = min(cnt[bx], CAP); // uniform broadcast load
    const float2* lst = lists + (size_t)bx * CAP;

    const int   t   = threadIdx.x;
    const int   py  = ty * TSZ + (t >> 3);
    const int   px0 = tx * TSZ + (t & 7) * 4;
    const float fpy = (float)py;

    float acc[4] = {0.0f, 0.0f, 0.0f, 0.0f};
    for (int j = 0; j < n; ++j) {
        float2 e = lst[j];                 // uniform broadcast, L2-hit
        int   i0   = (int)e.x;
        int   i1   = (int)e.y;
        float dy   = fpy - e.y;
        float dy2e = dy * dy + 1e-6f;
        bool  in1  = (unsigned)(py - i1 + HALF) <= (unsigned)(2 * HALF);
        #pragma unroll
        for (int c = 0; c < 4; ++c) {
            int   px  = px0 + c;
            float dx  = (float)px - e.x;
            bool  in0 = (unsigned)(px - i0 + HALF) <= (unsigned)(2 * HALF);
            // val = 1/(1+sqrt(d2)); hw sqrt+rcp ~1 ulp, threshold 4.3e-2
            float v = __builtin_amdgcn_rcpf(1.0f + __builtin_amdgcn_sqrtf(dx * dx + dy2e));
            acc[c] += (in0 && in1) ? v : 0.0f;
        }
    }

    float* op = out + (size_t)b * (IMH * IMW) + (size_t)py * IMW + px0;
    f32x4 v4 = { acc[0], acc[1], acc[2], acc[3] };
    *reinterpret_cast<f32x4*>(op) = v4;
}

extern "C" void kernel_launch(void* const* d_in, const int* in_sizes, int n_in,
                              void* d_out, int out_size, void* d_ws, size_t ws_size,
                              hipStream_t stream)
{
    // d_in[0] = img (unused by the reference); d_in[1] = landmarks [B, L, 2] f32
    const float* landmarks = (const float*)d_in[1];
    float* out = (float*)d_out;

    const int B = out_size / (IMH * IMW);   // 64
    const int L = in_sizes[1] / (2 * B);    // 106

    // ws: [cnt: B*TPI int][lists: B*TPI*CAP float2]  = 64 KB + 6.3 MB
    int*    cnt   = (int*)d_ws;
    float2* lists = (float2*)((char*)d_ws + (size_t)B * TPI * sizeof(int));

    lm_bin_kernel<<<B, 256, 0, stream>>>(landmarks, L, cnt, lists);
    lm_gather_kernel<<<B * TPI, 256, 0, stream>>>(cnt, lists, out);
}

// Round 9
// 24.472 us; speedup vs baseline: 1.0523x; 1.0523x over previous
//
#include <hip/hip_runtime.h>

#define HALF 16
#define IMW  512
#define IMH  512
#define TSZ  32                 // tile size
#define NT   16                 // tiles per axis
#define SPB  8                  // tiles (subtiles) per block: 256x32 strip
#define BPI  32                 // blocks per image (16 rows x 2 half-rows)
#define CAP  48                 // per-subtile list capacity (avg ~1.7)

typedef float f32x4 __attribute__((ext_vector_type(4)));

// One block per 256x32 strip (8 adjacent 32x32 tiles of one tile-row).
// Rationale (r8 ledger): every store/eval/swizzle/phase-1 variant lands at
// ~24 us => the residual is accumulated per-block cost (dispatch, dependent
// list loads, store drain) x 16384 tiny blocks + ~2 us per launch. This
// kernel: 1 launch, 2048 blocks (8/CU), 1 landmark scan per block binned
// into 8 LDS lists, 1 barrier, then 8 tiles back-to-back from LDS.
__global__ __launch_bounds__(256)
void lm_strip8_kernel(const float* __restrict__ landmarks,  // [B, L, 2]
                      float* __restrict__ out,              // [B, IMH*IMW]
                      int L)
{
    __shared__ float2 slist[SPB][CAP];
    __shared__ int    scnt[SPB];

    const int t   = threadIdx.x;
    const int bx  = blockIdx.x;
    const int b   = bx >> 5;             // BPI == 32
    const int rem = bx & (BPI - 1);
    const int ty  = rem >> 1;            // tile row 0..15
    const int tx0 = (rem & 1) * SPB;     // first tile col: 0 or 8
    const int R   = ty * TSZ;            // strip rows [R, R+32)
    const int C0  = tx0 * TSZ;           // strip cols [C0, C0+256)

    if (t < SPB) scnt[t] = 0;
    __syncthreads();

    // Phase 1: one scan of this image's landmarks -> up to 2 of 8 lists each.
    const float2* lmb = reinterpret_cast<const float2*>(landmarks) + (size_t)b * L;
    for (int j = t; j < L; j += 256) {
        float2 lm = lmb[j];
        float x0 = fminf(fmaxf(lm.x, (float)HALF), (float)(IMW - 1 - HALF));
        float x1 = fminf(fmaxf(lm.y, (float)HALF), (float)(IMH - 1 - HALF));
        int i0 = (int)x0;                // coords >= 16, trunc == floor
        int i1 = (int)x1;
        // rows: patch [i1-16, i1+16] must intersect [R, R+32)
        if ((unsigned)(i1 - (R - HALF)) < (unsigned)(TSZ + 2 * HALF)) {
            // cols: patch spans exactly tiles {g0, g0+1} in the global grid
            int g0 = (i0 - HALF) >> 5;
            #pragma unroll
            for (int d = 0; d < 2; ++d) {
                int s = g0 + d - tx0;    // subtile index within this strip
                if ((unsigned)s < (unsigned)SPB) {
                    int pos = atomicAdd(&scnt[s], 1);
                    if (pos < CAP) slist[s][pos] = make_float2(x0, x1);
                }
            }
        }
    }
    __syncthreads();

    // Phase 2: 8 tiles back-to-back; py fixed per thread across tiles.
    const int   py  = R + (t >> 3);
    const int   c4  = (t & 7) * 4;       // col base within a tile
    const float fpy = (float)py;
    float* orow = out + (size_t)b * (IMH * IMW) + (size_t)py * IMW;

    for (int s = 0; s < SPB; ++s) {
        const int n   = min(scnt[s], CAP);
        const int px0 = C0 + s * TSZ + c4;
        float acc[4] = {0.0f, 0.0f, 0.0f, 0.0f};
        for (int j = 0; j < n; ++j) {
            float2 e = slist[s][j];      // LDS broadcast, conflict-free
            int   i0   = (int)e.x;
            int   i1   = (int)e.y;
            float dy   = fpy - e.y;
            float dy2e = dy * dy + 1e-6f;
            bool  in1  = (unsigned)(py - i1 + HALF) <= (unsigned)(2 * HALF);
            #pragma unroll
            for (int c = 0; c < 4; ++c) {
                int   px  = px0 + c;
                float dx  = (float)px - e.x;
                bool  in0 = (unsigned)(px - i0 + HALF) <= (unsigned)(2 * HALF);
                // val = 1/(1+sqrt(d2)); hw sqrt+rcp ~1 ulp, threshold 4.3e-2
                float v = __builtin_amdgcn_rcpf(1.0f + __builtin_amdgcn_sqrtf(dx * dx + dy2e));
                acc[c] += (in0 && in1) ? v : 0.0f;
            }
        }
        f32x4 v4 = { acc[0], acc[1], acc[2], acc[3] };
        *reinterpret_cast<f32x4*>(orow + px0) = v4;   // fire-and-forget
    }
}

extern "C" void kernel_launch(void* const* d_in, const int* in_sizes, int n_in,
                              void* d_out, int out_size, void* d_ws, size_t ws_size,
                              hipStream_t stream)
{
    // d_in[0] = img (unused by the reference); d_in[1] = landmarks [B, L, 2] f32
    const float* landmarks = (const float*)d_in[1];
    float* out = (float*)d_out;

    const int B = out_size / (IMH * IMW);   // 64
    const int L = in_sizes[1] / (2 * B);    // 106

    lm_strip8_kernel<<<B * BPI, 256, 0, stream>>>(landmarks, out, L);
}